// Round 9
// baseline (215.850 us; speedup 1.0000x reference)
//
#include <hip/hip_runtime.h>

#define BB 2
#define NN 1024
#define FF 128
#define H1 64
#define H2 32
#define XPAD 136  // x-row stride in f16 (128+8)
#define PAD 72    // p-row stride in f16 (64+8)
#define REPS 16   // INSTRUMENTATION: phase-B repeat count (idempotent stores)

typedef __attribute__((ext_vector_type(4))) _Float16 half4;   // 4 f16 (8B)
typedef __attribute__((ext_vector_type(8))) _Float16 half8;   // 8 f16 (4 VGPR)
typedef __attribute__((ext_vector_type(16))) float f32x16;    // 32x32 MFMA acc

// e = relu(a + b) in packed f16: 4x v_pk_add_f16 + 4x v_pk_max_f16
__device__ inline half8 addrelu8(half8 a, half8 b) {
    half8 s = a + b;
    const half8 z = {};
    return __builtin_elementwise_max(s, z);
}

// ---------------------------------------------------------------------------
// INSTRUMENTATION ROUND (R9). R8's kernel is 26.1us but hides below the 40us
// fill dispatches in rocprof top-5; every static model of phase B says
// ~4-5us, a 4x disagreement I cannot localize without counters. This kernel
// = R8 with phase B repeated REPS=16x (stores are idempotent; an opaque
// "+v" asm on the qj fragments each rep defeats cross-rep CSE/DCE, rule #17).
//   dur16 = A + 16*E,  dur1 = A + E = 26.1  =>  E = (dur16-26.1)/15 exactly,
// and the kernel lands #1 in top-5 so VALUBusy/MfmaUtil/Occupancy/LDS
// conflicts become visible. Pre-committed branches:
//   dur16~320 => E~20 steady-state; counters say which pipe.
//   dur16~80  => E~3.5, A~22 => phase A cold-memory is the monster.
// R8 (REPS=1) remains the recoverable best.
// ---------------------------------------------------------------------------
__global__ __launch_bounds__(256, 4) void fused_kernel(
    const float* __restrict__ x, const float* __restrict__ W1,
    const float* __restrict__ b1, const float* __restrict__ W2,
    const float* __restrict__ b2, const float* __restrict__ W3,
    const float* __restrict__ b3, float* __restrict__ out)
{
    __shared__ __align__(16) _Float16 xlds[96][XPAD];  // 26.1 KB staged x (f16)
    __shared__ __align__(16) _Float16 plds[64][PAD];   // 9.2 KB pib rows
    __shared__ __align__(16) _Float16 pjlds[32][PAD];  // 4.6 KB pj rows

    const int tid  = threadIdx.x;
    const int lane = tid & 63;
    const int wv   = tid >> 6;
    const int bid  = blockIdx.x;

    const int b   = bid >> 9;                 // 512 blocks per batch
    const int rem = bid & 511;
    const int i0  = (rem >> 5) * 64;          // 16 i-tiles (64 rows each)
    const int j0  = (rem & 31) * 32;          // 32 j-tiles (32 cols each)
    const int jn  = lane & 31;                // m/n lane index
    const int hi  = lane >> 5;                // k-group half
    const int m   = jn;

    // ============ stage: 96 x-rows -> xlds (coalesced, f16) ===============
    {
        const int xb_i = b * NN + i0, xb_j = b * NN + j0 - 64;
        #pragma unroll
        for (int it = 0; it < 12; ++it) {
            const int idx = tid + it * 256;
            const int row = idx >> 5, c4 = (idx & 31) * 4;
            const int gr  = (row < 64 ? xb_i : xb_j) + row;
            const float4 v = *(const float4*)(x + (size_t)gr * FF + c4);
            half4 hv = {(_Float16)v.x, (_Float16)v.y,
                        (_Float16)v.z, (_Float16)v.w};
            *(half4*)&xlds[row][c4] = hv;
        }
    }
    __syncthreads();

    // ============ phase A: 6 gemm units (32 rows x 32 h each) =============
    auto gemm_unit = [&](int xrow0, int htile, int koff,
                         _Float16* dstbase, const float* bias) {
        f32x16 acc = {};
        #pragma unroll
        for (int ks = 0; ks < 8; ++ks) {
            const int k0 = ks * 16 + hi * 8;
            half8 af;
            const float* wb = W1 + (size_t)(koff + k0) * H1 + htile * 32 + m;
            #pragma unroll
            for (int e = 0; e < 8; ++e)
                af[e] = (_Float16)wb[(size_t)e * H1];     // coalesced per e
            const half8 bf = *(const half8*)&xlds[xrow0 + m][k0];
            acc = __builtin_amdgcn_mfma_f32_32x32x16_f16(af, bf, acc, 0, 0, 0);
        }
        _Float16* drow = dstbase + (size_t)m * PAD;       // D col -> LDS row
        #pragma unroll
        for (int q = 0; q < 4; ++q) {                     // packed b64 stores
            half4 hv;
            #pragma unroll
            for (int jj = 0; jj < 4; ++jj) {
                const int r  = q * 4 + jj;                // hl=(r&3)+8(r>>2)+4hi
                const int hg = htile * 32 + 8 * q + 4 * hi + jj;
                float v = acc[r];
                if (bias) v += bias[hg];
                hv[jj] = (_Float16)v;
            }
            *(half4*)(drow + htile * 32 + 8 * q + 4 * hi) = hv;
        }
    };
    if (wv == 0) {
        gemm_unit(0,  0, FF, &plds[0][0],  b1);       // pib rows 0-31, h 0-31
        gemm_unit(64, 0, 0,  &pjlds[0][0], nullptr);  // pj  rows 0-31, h 0-31
    } else if (wv == 1) {
        gemm_unit(0,  1, FF, &plds[0][0],  b1);       // pib rows 0-31, h 32-63
        gemm_unit(64, 1, 0,  &pjlds[0][0], nullptr);  // pj  rows 0-31, h 32-63
    } else if (wv == 2) {
        gemm_unit(32, 0, FF, &plds[32][0], b1);       // pib rows 32-63, h 0-31
    } else {
        gemm_unit(32, 1, FF, &plds[32][0], b1);       // pib rows 32-63, h 32-63
    }

    // ============ per-wave edge init (weights straight from global) =======
    half8 wa[4];
    #pragma unroll
    for (int c4 = 0; c4 < 4; ++c4)
        #pragma unroll
        for (int e = 0; e < 8; ++e)
            wa[c4][e] = (_Float16)W2[(16 * c4 + hi * 8 + e) * H2 + jn];

    f32x16 ci;
    float w3r[16];
    #pragma unroll
    for (int r = 0; r < 16; ++r) {           // D row mapping [m74/m101]
        const int row = (r & 3) + 8 * (r >> 2) + 4 * hi;
        ci[r]  = b2[row];
        w3r[r] = W3[row];
    }
    const float b3v = b3[0];

    __syncthreads();   // phase A LDS writes visible to all waves

    // B-frags (pj side) from LDS: row j0+jn, k-slices 16c + hi*8
    const _Float16* pr = &pjlds[jn][hi * 8];
    half8 qj0 = *(const half8*)(pr);
    half8 qj1 = *(const half8*)(pr + 16);
    half8 qj2 = *(const half8*)(pr + 32);
    half8 qj3 = *(const half8*)(pr + 48);

    // ============ phase B x REPS (instrumented) ===========================
    const int srow = wv * 16;
    const _Float16* irbase = &plds[srow][hi * 8];
    float* obase = out + (size_t)(b * NN + i0 + srow) * NN + j0 + jn;

    #pragma unroll 1
    for (int rep = 0; rep < REPS; ++rep) {
        // opaque touch: compiler must treat qj as fresh -> no cross-rep CSE
        asm volatile("" : "+v"(qj0), "+v"(qj1), "+v"(qj2), "+v"(qj3));

        half8 c0 = *(const half8*)(irbase);
        half8 c1 = *(const half8*)(irbase + 16);
        half8 c2 = *(const half8*)(irbase + 32);
        half8 c3 = *(const half8*)(irbase + 48);
        half8 n0, n1, n2, n3;
        float pe = 0.f;

        #pragma unroll 1
        for (int t = 0; t < 16; ++t) {
            if (t < 15) {                        // 1-row LDS lookahead
                const _Float16* ir = irbase + (t + 1) * PAD;
                n0 = *(const half8*)(ir);
                n1 = *(const half8*)(ir + 16);
                n2 = *(const half8*)(ir + 32);
                n3 = *(const half8*)(ir + 48);
            }
            half8 e0 = addrelu8(qj0, c0);
            half8 e1 = addrelu8(qj1, c1);
            half8 e2 = addrelu8(qj2, c2);
            half8 e3 = addrelu8(qj3, c3);
            f32x16 d;
            d = __builtin_amdgcn_mfma_f32_32x32x16_f16(wa[0], e0, ci, 0, 0, 0);
            d = __builtin_amdgcn_mfma_f32_32x32x16_f16(wa[1], e1, d,  0, 0, 0);
            d = __builtin_amdgcn_mfma_f32_32x32x16_f16(wa[2], e2, d,  0, 0, 0);
            d = __builtin_amdgcn_mfma_f32_32x32x16_f16(wa[3], e3, d,  0, 0, 0);
            float p0 = 0.f, p1 = 0.f, p2 = 0.f, p3 = 0.f;
            #pragma unroll
            for (int r = 0; r < 4; ++r) {
                p0 = fmaf(fmaxf(d[r],      0.f), w3r[r],      p0);
                p1 = fmaf(fmaxf(d[4 + r],  0.f), w3r[4 + r],  p1);
                p2 = fmaf(fmaxf(d[8 + r],  0.f), w3r[8 + r],  p2);
                p3 = fmaf(fmaxf(d[12 + r], 0.f), w3r[12 + r], p3);
            }
            float p = (p0 + p1) + (p2 + p3);
            p += __shfl_xor(p, 32);
            if (t & 1) {                         // store a 2-row pair
                float v = hi ? p : pe;
                obase[(size_t)(t - 1 + hi) * NN] = v + b3v;
            } else {
                pe = p;
            }
            c0 = n0; c1 = n1; c2 = n2; c3 = n3;
        }
    }
}

extern "C" void kernel_launch(void* const* d_in, const int* in_sizes, int n_in,
                              void* d_out, int out_size, void* d_ws, size_t ws_size,
                              hipStream_t stream) {
    const float* x  = (const float*)d_in[0];
    // d_in[1] = adj (UNUSED by reference), d_in[2] = mask (UNUSED)
    const float* W1 = (const float*)d_in[3];
    const float* b1 = (const float*)d_in[4];
    const float* W2 = (const float*)d_in[5];
    const float* b2 = (const float*)d_in[6];
    const float* W3 = (const float*)d_in[7];
    const float* b3 = (const float*)d_in[8];
    float* out = (float*)d_out;

    // single self-sufficient launch; workspace unused
    fused_kernel<<<BB * NN / 2, 256, 0, stream>>>(
        x, W1, b1, W2, b2, W3, b3, out);
}

// Round 10
// 25.146 us; speedup vs baseline: 8.5838x; 8.5838x over previous
//
#include <hip/hip_runtime.h>

#define BB 2
#define NN 1024
#define FF 128
#define H1 64
#define H2 32
#define XPAD 136  // x-row stride in f16 (128+8)
#define PAD 72    // p-row stride in f16 (64+8)

typedef __attribute__((ext_vector_type(4))) _Float16 half4;   // 4 f16 (8B)
typedef __attribute__((ext_vector_type(8))) _Float16 half8;   // 8 f16 (4 VGPR)
typedef __attribute__((ext_vector_type(16))) float f32x16;    // 32x32 MFMA acc
typedef __attribute__((ext_vector_type(2))) float f32x2;      // v_pk_*_f32

// e = relu(a + b) in packed f16: 4x v_pk_add_f16 + 4x v_pk_max_f16
__device__ inline half8 addrelu8(half8 a, half8 b) {
    half8 s = a + b;
    const half8 z = {};
    return __builtin_elementwise_max(s, z);
}

// ---------------------------------------------------------------------------
// ZERO-SYNC full fusion, v3. R9 instrumentation (REPS=16): phase B = 12.7us,
// VALUBusy 73% / MfmaUtil 26% -> B is VALU-ISSUE-bound; phase A+stage =
// 13.5us. This round cuts phase-B VALU:
//  (1) packed-f32 epilogue: d as 8 float2 pairs, v_pk_max_f32 + v_pk_fma_f32
//      (8+8+3+1 insts vs 32 max + 32 fma + reduce) — identical fma rounding;
//  (2) #pragma unroll 2 on the t-loop: register renaming kills the ~24
//      v_mov/step pipeline-rotate that unroll 1 forced.
// Phase A untouched (next round's target: its W1 strided loads).
// ---------------------------------------------------------------------------
__global__ __launch_bounds__(256, 4) void fused_kernel(
    const float* __restrict__ x, const float* __restrict__ W1,
    const float* __restrict__ b1, const float* __restrict__ W2,
    const float* __restrict__ b2, const float* __restrict__ W3,
    const float* __restrict__ b3, float* __restrict__ out)
{
    __shared__ __align__(16) _Float16 xlds[96][XPAD];  // 26.1 KB staged x (f16)
    __shared__ __align__(16) _Float16 plds[64][PAD];   // 9.2 KB pib rows
    __shared__ __align__(16) _Float16 pjlds[32][PAD];  // 4.6 KB pj rows

    const int tid  = threadIdx.x;
    const int lane = tid & 63;
    const int wv   = tid >> 6;
    const int bid  = blockIdx.x;

    const int b   = bid >> 9;                 // 512 blocks per batch
    const int rem = bid & 511;
    const int i0  = (rem >> 5) * 64;          // 16 i-tiles (64 rows each)
    const int j0  = (rem & 31) * 32;          // 32 j-tiles (32 cols each)
    const int jn  = lane & 31;                // m/n lane index
    const int hi  = lane >> 5;                // k-group half
    const int m   = jn;

    // ============ stage: 96 x-rows -> xlds (coalesced, f16) ===============
    {
        const int xb_i = b * NN + i0, xb_j = b * NN + j0 - 64;
        #pragma unroll
        for (int it = 0; it < 12; ++it) {
            const int idx = tid + it * 256;
            const int row = idx >> 5, c4 = (idx & 31) * 4;
            const int gr  = (row < 64 ? xb_i : xb_j) + row;
            const float4 v = *(const float4*)(x + (size_t)gr * FF + c4);
            half4 hv = {(_Float16)v.x, (_Float16)v.y,
                        (_Float16)v.z, (_Float16)v.w};
            *(half4*)&xlds[row][c4] = hv;
        }
    }
    __syncthreads();

    // ============ phase A: 6 gemm units (32 rows x 32 h each) =============
    auto gemm_unit = [&](int xrow0, int htile, int koff,
                         _Float16* dstbase, const float* bias) {
        f32x16 acc = {};
        #pragma unroll
        for (int ks = 0; ks < 8; ++ks) {
            const int k0 = ks * 16 + hi * 8;
            half8 af;
            const float* wb = W1 + (size_t)(koff + k0) * H1 + htile * 32 + m;
            #pragma unroll
            for (int e = 0; e < 8; ++e)
                af[e] = (_Float16)wb[(size_t)e * H1];     // coalesced per e
            const half8 bf = *(const half8*)&xlds[xrow0 + m][k0];
            acc = __builtin_amdgcn_mfma_f32_32x32x16_f16(af, bf, acc, 0, 0, 0);
        }
        _Float16* drow = dstbase + (size_t)m * PAD;       // D col -> LDS row
        #pragma unroll
        for (int q = 0; q < 4; ++q) {                     // packed b64 stores
            half4 hv;
            #pragma unroll
            for (int jj = 0; jj < 4; ++jj) {
                const int r  = q * 4 + jj;                // hl=(r&3)+8(r>>2)+4hi
                const int hg = htile * 32 + 8 * q + 4 * hi + jj;
                float v = acc[r];
                if (bias) v += bias[hg];
                hv[jj] = (_Float16)v;
            }
            *(half4*)(drow + htile * 32 + 8 * q + 4 * hi) = hv;
        }
    };
    if (wv == 0) {
        gemm_unit(0,  0, FF, &plds[0][0],  b1);       // pib rows 0-31, h 0-31
        gemm_unit(64, 0, 0,  &pjlds[0][0], nullptr);  // pj  rows 0-31, h 0-31
    } else if (wv == 1) {
        gemm_unit(0,  1, FF, &plds[0][0],  b1);       // pib rows 0-31, h 32-63
        gemm_unit(64, 1, 0,  &pjlds[0][0], nullptr);  // pj  rows 0-31, h 32-63
    } else if (wv == 2) {
        gemm_unit(32, 0, FF, &plds[32][0], b1);       // pib rows 32-63, h 0-31
    } else {
        gemm_unit(32, 1, FF, &plds[32][0], b1);       // pib rows 32-63, h 32-63
    }

    // ============ per-wave edge init (weights straight from global) =======
    half8 wa[4];
    #pragma unroll
    for (int c4 = 0; c4 < 4; ++c4)
        #pragma unroll
        for (int e = 0; e < 8; ++e)
            wa[c4][e] = (_Float16)W2[(16 * c4 + hi * 8 + e) * H2 + jn];

    f32x16 ci;
    #pragma unroll
    for (int r = 0; r < 16; ++r) {           // D row mapping [m74/m101]
        const int row = (r & 3) + 8 * (r >> 2) + 4 * hi;
        ci[r] = b2[row];
    }
    // W3 paired for the packed epilogue: pair q covers rows (base, base+1),
    // base = (2q&3) + 8*(q>>1) + 4*hi  (consecutive rows within a d-pair)
    f32x2 w32[8];
    #pragma unroll
    for (int q = 0; q < 8; ++q) {
        const int row = ((2 * q) & 3) + 8 * (q >> 1) + 4 * hi;
        w32[q] = (f32x2){W3[row], W3[row + 1]};
    }
    const float b3v = b3[0];

    __syncthreads();   // phase A LDS writes visible to all waves

    // B-frags (pj side) from LDS: row j0+jn, k-slices 16c + hi*8
    const _Float16* pr = &pjlds[jn][hi * 8];
    const half8 qj0 = *(const half8*)(pr);
    const half8 qj1 = *(const half8*)(pr + 16);
    const half8 qj2 = *(const half8*)(pr + 32);
    const half8 qj3 = *(const half8*)(pr + 48);

    // ============ phase B: 16 row-steps, 1-row LDS lookahead ==============
    const int srow = wv * 16;
    const _Float16* irbase = &plds[srow][hi * 8];
    float* obase = out + (size_t)(b * NN + i0 + srow) * NN + j0 + jn;

    half8 c0 = *(const half8*)(irbase);
    half8 c1 = *(const half8*)(irbase + 16);
    half8 c2 = *(const half8*)(irbase + 32);
    half8 c3 = *(const half8*)(irbase + 48);
    half8 n0, n1, n2, n3;
    float pe = 0.f;

    #pragma unroll 2
    for (int t = 0; t < 16; ++t) {
        if (t < 15) {                        // 1-row LDS lookahead
            const _Float16* ir = irbase + (t + 1) * PAD;
            n0 = *(const half8*)(ir);
            n1 = *(const half8*)(ir + 16);
            n2 = *(const half8*)(ir + 32);
            n3 = *(const half8*)(ir + 48);
        }
        half8 e0 = addrelu8(qj0, c0);        // c* dies into e* (no reg growth)
        half8 e1 = addrelu8(qj1, c1);
        half8 e2 = addrelu8(qj2, c2);
        half8 e3 = addrelu8(qj3, c3);
        f32x16 d;
        d = __builtin_amdgcn_mfma_f32_32x32x16_f16(wa[0], e0, ci, 0, 0, 0);
        d = __builtin_amdgcn_mfma_f32_32x32x16_f16(wa[1], e1, d,  0, 0, 0);
        d = __builtin_amdgcn_mfma_f32_32x32x16_f16(wa[2], e2, d,  0, 0, 0);
        d = __builtin_amdgcn_mfma_f32_32x32x16_f16(wa[3], e3, d,  0, 0, 0);

        // packed-f32 epilogue: 8 pk_max + 8 pk_fma + 3 pk_add + 1 add
        const f32x2 z2 = {0.f, 0.f};
        f32x2 s[4] = {z2, z2, z2, z2};
        #pragma unroll
        for (int q = 0; q < 8; ++q) {        // q compile-time -> static idx
            f32x2 dp = {d[2 * q], d[2 * q + 1]};
            dp = __builtin_elementwise_max(dp, z2);
            s[q & 3] = __builtin_elementwise_fma(dp, w32[q], s[q & 3]);
        }
        const f32x2 t01 = s[0] + s[1];
        const f32x2 t23 = s[2] + s[3];
        const f32x2 tt  = t01 + t23;
        float p = tt[0] + tt[1];
        p += __shfl_xor(p, 32);              // lane-halves hold complementary rows
        if (t & 1) {                         // store a 2-row pair, full-wave
            float v = hi ? p : pe;           // hi half stores the odd row
            obase[(size_t)(t - 1 + hi) * NN] = v + b3v;
        } else {
            pe = p;
        }
        c0 = n0; c1 = n1; c2 = n2; c3 = n3;  // renamed away under unroll 2
    }
}

extern "C" void kernel_launch(void* const* d_in, const int* in_sizes, int n_in,
                              void* d_out, int out_size, void* d_ws, size_t ws_size,
                              hipStream_t stream) {
    const float* x  = (const float*)d_in[0];
    // d_in[1] = adj (UNUSED by reference), d_in[2] = mask (UNUSED)
    const float* W1 = (const float*)d_in[3];
    const float* b1 = (const float*)d_in[4];
    const float* W2 = (const float*)d_in[5];
    const float* b2 = (const float*)d_in[6];
    const float* W3 = (const float*)d_in[7];
    const float* b3 = (const float*)d_in[8];
    float* out = (float*)d_out;

    // single self-sufficient launch; workspace unused
    fused_kernel<<<BB * NN / 2, 256, 0, stream>>>(
        x, W1, b1, W2, b2, W3, b3, out);
}

// Round 11
// 24.715 us; speedup vs baseline: 8.7336x; 1.0174x over previous
//
#include <hip/hip_runtime.h>

#define BB 2
#define NN 1024
#define FF 128
#define H1 64
#define H2 32
#define XPAD 136  // x-row stride in f16 (128+8)
#define PAD 72    // p-row stride in f16 (64+8)

typedef __attribute__((ext_vector_type(4))) _Float16 half4;   // 4 f16 (8B)
typedef __attribute__((ext_vector_type(8))) _Float16 half8;   // 8 f16 (4 VGPR)
typedef __attribute__((ext_vector_type(16))) float f32x16;    // 32x32 MFMA acc
typedef __attribute__((ext_vector_type(2))) float f32x2;      // v_pk_*_f32

// e = relu(a + b) in packed f16: 4x v_pk_add_f16 + 4x v_pk_max_f16
__device__ inline half8 addrelu8(half8 a, half8 b) {
    half8 s = a + b;
    const half8 z = {};
    return __builtin_elementwise_max(s, z);
}

// ---------------------------------------------------------------------------
// ZERO-SYNC full fusion, v4. R9 counters: per-step wall 475cy = VALU 347 +
// MFMA 122, additive (73% + 26% = 99%) -> the waves time-slice the two pipes
// instead of overlapping: each step's E-build feeds its MFMA chain directly,
// so the 4-deep dependent MFMA chain's ~128cy latency is fully exposed.
// v4 software-pipelines phase B:
//   - E-fragments are built ONE STEP AHEAD (from LDS rows prefetched at the
//     top of the iteration),
//   - the relu-dot epilogue runs ONE STEP BEHIND (on d(t-1)),
// so the VALU work inside an iteration is independent of the in-flight MFMA
// chain and the scheduler can interleave them. Phase A untouched (R9
// attribution: stage+A ~13.5us — next target).
// ---------------------------------------------------------------------------
__global__ __launch_bounds__(256, 4) void fused_kernel(
    const float* __restrict__ x, const float* __restrict__ W1,
    const float* __restrict__ b1, const float* __restrict__ W2,
    const float* __restrict__ b2, const float* __restrict__ W3,
    const float* __restrict__ b3, float* __restrict__ out)
{
    __shared__ __align__(16) _Float16 xlds[96][XPAD];  // 26.1 KB staged x (f16)
    __shared__ __align__(16) _Float16 plds[64][PAD];   // 9.2 KB pib rows
    __shared__ __align__(16) _Float16 pjlds[32][PAD];  // 4.6 KB pj rows

    const int tid  = threadIdx.x;
    const int lane = tid & 63;
    const int wv   = tid >> 6;
    const int bid  = blockIdx.x;

    const int b   = bid >> 9;                 // 512 blocks per batch
    const int rem = bid & 511;
    const int i0  = (rem >> 5) * 64;          // 16 i-tiles (64 rows each)
    const int j0  = (rem & 31) * 32;          // 32 j-tiles (32 cols each)
    const int jn  = lane & 31;                // m/n lane index
    const int hi  = lane >> 5;                // k-group half
    const int m   = jn;

    // ============ stage: 96 x-rows -> xlds (coalesced, f16) ===============
    {
        const int xb_i = b * NN + i0, xb_j = b * NN + j0 - 64;
        #pragma unroll
        for (int it = 0; it < 12; ++it) {
            const int idx = tid + it * 256;
            const int row = idx >> 5, c4 = (idx & 31) * 4;
            const int gr  = (row < 64 ? xb_i : xb_j) + row;
            const float4 v = *(const float4*)(x + (size_t)gr * FF + c4);
            half4 hv = {(_Float16)v.x, (_Float16)v.y,
                        (_Float16)v.z, (_Float16)v.w};
            *(half4*)&xlds[row][c4] = hv;
        }
    }
    __syncthreads();

    // ============ phase A: 6 gemm units (32 rows x 32 h each) =============
    auto gemm_unit = [&](int xrow0, int htile, int koff,
                         _Float16* dstbase, const float* bias) {
        f32x16 acc = {};
        #pragma unroll
        for (int ks = 0; ks < 8; ++ks) {
            const int k0 = ks * 16 + hi * 8;
            half8 af;
            const float* wb = W1 + (size_t)(koff + k0) * H1 + htile * 32 + m;
            #pragma unroll
            for (int e = 0; e < 8; ++e)
                af[e] = (_Float16)wb[(size_t)e * H1];     // coalesced per e
            const half8 bf = *(const half8*)&xlds[xrow0 + m][k0];
            acc = __builtin_amdgcn_mfma_f32_32x32x16_f16(af, bf, acc, 0, 0, 0);
        }
        _Float16* drow = dstbase + (size_t)m * PAD;       // D col -> LDS row
        #pragma unroll
        for (int q = 0; q < 4; ++q) {                     // packed b64 stores
            half4 hv;
            #pragma unroll
            for (int jj = 0; jj < 4; ++jj) {
                const int r  = q * 4 + jj;                // hl=(r&3)+8(r>>2)+4hi
                const int hg = htile * 32 + 8 * q + 4 * hi + jj;
                float v = acc[r];
                if (bias) v += bias[hg];
                hv[jj] = (_Float16)v;
            }
            *(half4*)(drow + htile * 32 + 8 * q + 4 * hi) = hv;
        }
    };
    if (wv == 0) {
        gemm_unit(0,  0, FF, &plds[0][0],  b1);       // pib rows 0-31, h 0-31
        gemm_unit(64, 0, 0,  &pjlds[0][0], nullptr);  // pj  rows 0-31, h 0-31
    } else if (wv == 1) {
        gemm_unit(0,  1, FF, &plds[0][0],  b1);       // pib rows 0-31, h 32-63
        gemm_unit(64, 1, 0,  &pjlds[0][0], nullptr);  // pj  rows 0-31, h 32-63
    } else if (wv == 2) {
        gemm_unit(32, 0, FF, &plds[32][0], b1);       // pib rows 32-63, h 0-31
    } else {
        gemm_unit(32, 1, FF, &plds[32][0], b1);       // pib rows 32-63, h 32-63
    }

    // ============ per-wave edge init (weights straight from global) =======
    half8 wa[4];
    #pragma unroll
    for (int c4 = 0; c4 < 4; ++c4)
        #pragma unroll
        for (int e = 0; e < 8; ++e)
            wa[c4][e] = (_Float16)W2[(16 * c4 + hi * 8 + e) * H2 + jn];

    f32x16 ci;
    #pragma unroll
    for (int r = 0; r < 16; ++r) {           // D row mapping [m74/m101]
        const int row = (r & 3) + 8 * (r >> 2) + 4 * hi;
        ci[r] = b2[row];
    }
    // W3 paired for the packed epilogue (R10 layout, verified)
    f32x2 w32[8];
    #pragma unroll
    for (int q = 0; q < 8; ++q) {
        const int row = ((2 * q) & 3) + 8 * (q >> 1) + 4 * hi;
        w32[q] = (f32x2){W3[row], W3[row + 1]};
    }
    const float b3v = b3[0];

    __syncthreads();   // phase A LDS writes visible to all waves

    // B-frags (pj side) from LDS: row j0+jn, k-slices 16c + hi*8
    const _Float16* pr = &pjlds[jn][hi * 8];
    const half8 qj0 = *(const half8*)(pr);
    const half8 qj1 = *(const half8*)(pr + 16);
    const half8 qj2 = *(const half8*)(pr + 32);
    const half8 qj3 = *(const half8*)(pr + 48);

    // R10 packed epilogue (incl. cross-half shfl), reused at 3 sites
    auto epi = [&](const f32x16& dd) -> float {
        const f32x2 z2 = {0.f, 0.f};
        f32x2 s[4] = {z2, z2, z2, z2};
        #pragma unroll
        for (int q = 0; q < 8; ++q) {
            f32x2 dp = {dd[2 * q], dd[2 * q + 1]};
            dp = __builtin_elementwise_max(dp, z2);
            s[q & 3] = __builtin_elementwise_fma(dp, w32[q], s[q & 3]);
        }
        const f32x2 t01 = s[0] + s[1];
        const f32x2 t23 = s[2] + s[3];
        const f32x2 tt  = t01 + t23;
        float p = tt[0] + tt[1];
        p += __shfl_xor(p, 32);   // lane-halves hold complementary rows
        return p;
    };

    // ============ phase B: software-pipelined 16 row-steps ================
    const int srow = wv * 16;
    const _Float16* irbase = &plds[srow][hi * 8];
    float* obase = out + (size_t)(b * NN + i0 + srow) * NN + j0 + jn;

    // ---- prologue: e(0), dP = mfma(step 0), e(1) ----
    half8 e0 = addrelu8(qj0, *(const half8*)(irbase));
    half8 e1 = addrelu8(qj1, *(const half8*)(irbase + 16));
    half8 e2 = addrelu8(qj2, *(const half8*)(irbase + 32));
    half8 e3 = addrelu8(qj3, *(const half8*)(irbase + 48));
    f32x16 dP;
    dP = __builtin_amdgcn_mfma_f32_32x32x16_f16(wa[0], e0, ci, 0, 0, 0);
    dP = __builtin_amdgcn_mfma_f32_32x32x16_f16(wa[1], e1, dP, 0, 0, 0);
    dP = __builtin_amdgcn_mfma_f32_32x32x16_f16(wa[2], e2, dP, 0, 0, 0);
    dP = __builtin_amdgcn_mfma_f32_32x32x16_f16(wa[3], e3, dP, 0, 0, 0);
    {
        const _Float16* ir = irbase + PAD;
        e0 = addrelu8(qj0, *(const half8*)(ir));
        e1 = addrelu8(qj1, *(const half8*)(ir + 16));
        e2 = addrelu8(qj2, *(const half8*)(ir + 32));
        e3 = addrelu8(qj3, *(const half8*)(ir + 48));
    }
    float pe = 0.f;

    #pragma unroll 2
    for (int t = 1; t < 16; ++t) {
        // 1. prefetch LDS row for step t+1 (issue early; consumed at bottom)
        const int tn = (t < 15) ? t + 1 : 15;
        const _Float16* ir = irbase + tn * PAD;
        const half8 m0 = *(const half8*)(ir);
        const half8 m1 = *(const half8*)(ir + 16);
        const half8 m2 = *(const half8*)(ir + 32);
        const half8 m3 = *(const half8*)(ir + 48);
        // 2. MFMA chain of step t on e (built last iteration)
        f32x16 d;
        d = __builtin_amdgcn_mfma_f32_32x32x16_f16(wa[0], e0, ci, 0, 0, 0);
        d = __builtin_amdgcn_mfma_f32_32x32x16_f16(wa[1], e1, d,  0, 0, 0);
        d = __builtin_amdgcn_mfma_f32_32x32x16_f16(wa[2], e2, d,  0, 0, 0);
        d = __builtin_amdgcn_mfma_f32_32x32x16_f16(wa[3], e3, d,  0, 0, 0);
        // 3. epilogue of step t-1 (independent of the chain above)
        const float p = epi(dP);
        if ((t - 1) & 1) {                   // t even: store pair (t-2, t-1)
            const float v = hi ? p : pe;     // hi half stores the odd row
            obase[(size_t)(t - 2 + hi) * NN] = v + b3v;
        } else {
            pe = p;
        }
        // 4. build E for step t+1 (independent of the chain above)
        e0 = addrelu8(qj0, m0);
        e1 = addrelu8(qj1, m1);
        e2 = addrelu8(qj2, m2);
        e3 = addrelu8(qj3, m3);
        dP = d;
    }
    // ---- tail: epilogue of step 15, store pair (14,15) ----
    {
        const float p = epi(dP);
        const float v = hi ? p : pe;
        obase[(size_t)(14 + hi) * NN] = v + b3v;
    }
}

extern "C" void kernel_launch(void* const* d_in, const int* in_sizes, int n_in,
                              void* d_out, int out_size, void* d_ws, size_t ws_size,
                              hipStream_t stream) {
    const float* x  = (const float*)d_in[0];
    // d_in[1] = adj (UNUSED by reference), d_in[2] = mask (UNUSED)
    const float* W1 = (const float*)d_in[3];
    const float* b1 = (const float*)d_in[4];
    const float* W2 = (const float*)d_in[5];
    const float* b2 = (const float*)d_in[6];
    const float* W3 = (const float*)d_in[7];
    const float* b3 = (const float*)d_in[8];
    float* out = (float*)d_out;

    // single self-sufficient launch; workspace unused
    fused_kernel<<<BB * NN / 2, 256, 0, stream>>>(
        x, W1, b1, W2, b2, W3, b3, out);
}

// Round 12
// 22.995 us; speedup vs baseline: 9.3867x; 1.0748x over previous
//
#include <hip/hip_runtime.h>

#define BB 2
#define NN 1024
#define FF 128
#define H1 64
#define H2 32
#define XPAD 136  // x-row stride in f16 (128+8)
#define PAD 72    // p-row stride in f16 (64+8)

typedef __attribute__((ext_vector_type(4))) _Float16 half4;   // 4 f16 (8B)
typedef __attribute__((ext_vector_type(8))) _Float16 half8;   // 8 f16 (4 VGPR)
typedef __attribute__((ext_vector_type(16))) float f32x16;    // 32x32 MFMA acc
typedef __attribute__((ext_vector_type(2))) float f32x2;      // v_pk_*_f32

// e = relu(a + b) in packed f16: 4x v_pk_add_f16 + 4x v_pk_max_f16
__device__ inline half8 addrelu8(half8 a, half8 b) {
    half8 s = a + b;
    const half8 z = {};
    return __builtin_elementwise_max(s, z);
}

// ---------------------------------------------------------------------------
// ZERO-SYNC full fusion, v5: 8-wave blocks, 64x64 output tile.
// R9-R11 established: phase B is SIMD-issue-port-bound (VALUBusy 73% +
// MfmaUtil 26% = 99%; reordering null, inst cuts return ~proportional) and
// phase A+stage = 13.5us with two structural defects: 6 gemm-units over 4
// waves (2/2/1/1 imbalance -> phase-A wall = 2 serial units) and 96 staged
// x-rows per 64x32-tile block. v5: 512-thread blocks on 64x64 tiles ->
//   - phase A = 8 units over 8 waves, PERFECTLY balanced (wall = 1 unit),
//   - stage = 128 rows per 4x the outputs (-33% stage traffic),
//   - per-block fixed init halves (512 blocks),
//   - phase B per-wave byte-identical to R11 (wave -> rowgrp wv>>1, j-half
//     wv&1); occupancy unchanged (2 blk/CU x 8 waves = 16 waves/CU).
// LDS 52KB. All per-element arithmetic unchanged -> absmax unchanged.
// ---------------------------------------------------------------------------
__global__ __launch_bounds__(512, 4) void fused_kernel(
    const float* __restrict__ x, const float* __restrict__ W1,
    const float* __restrict__ b1, const float* __restrict__ W2,
    const float* __restrict__ b2, const float* __restrict__ W3,
    const float* __restrict__ b3, float* __restrict__ out)
{
    __shared__ __align__(16) _Float16 xlds[128][XPAD];  // 34.8 KB staged x
    __shared__ __align__(16) _Float16 plds[64][PAD];    // 9.2 KB pib rows
    __shared__ __align__(16) _Float16 pjlds[64][PAD];   // 9.2 KB pj rows

    const int tid  = threadIdx.x;
    const int lane = tid & 63;
    const int wv   = tid >> 6;                // 0..7
    const int bid  = blockIdx.x;

    const int b   = bid >> 8;                 // 256 blocks per batch
    const int rem = bid & 255;
    const int i0  = (rem >> 4) * 64;          // 16 i-tiles (64 rows each)
    const int j0  = (rem & 15) * 64;          // 16 j-tiles (64 cols each)
    const int jn  = lane & 31;                // m/n lane index
    const int hi  = lane >> 5;                // k-group half
    const int m   = jn;

    // ============ stage: 128 x-rows -> xlds (coalesced, f16) ==============
    // rows 0..63 = i-rows i0..i0+63; rows 64..127 = j-rows j0..j0+63.
    {
        const int xb_i = b * NN + i0, xb_j = b * NN + j0 - 64;
        #pragma unroll
        for (int it = 0; it < 8; ++it) {
            const int idx = tid + it * 512;
            const int row = idx >> 5, c4 = (idx & 31) * 4;
            const int gr  = (row < 64 ? xb_i : xb_j) + row;
            const float4 v = *(const float4*)(x + (size_t)gr * FF + c4);
            half4 hv = {(_Float16)v.x, (_Float16)v.y,
                        (_Float16)v.z, (_Float16)v.w};
            *(half4*)&xlds[row][c4] = hv;
        }
    }
    __syncthreads();

    // ============ phase A: 8 gemm units, ONE per wave (balanced) ==========
    //   wv0/1: pib rows  0-31 (htile 0/1)   wv2/3: pib rows 32-63
    //   wv4/5: pj  rows  0-31               wv6/7: pj  rows 32-63
    {
        const int xrow0 = ((wv & 2) ? 32 : 0) + ((wv & 4) ? 64 : 0);
        const int htile = wv & 1;
        const int koff  = (wv & 4) ? 0 : FF;
        _Float16* dstbase = (wv & 4) ? &pjlds[xrow0 - 64][0] : &plds[xrow0][0];
        const float* bias = (wv & 4) ? nullptr : b1;

        f32x16 acc = {};
        #pragma unroll
        for (int ks = 0; ks < 8; ++ks) {
            const int k0 = ks * 16 + hi * 8;
            half8 af;
            const float* wb = W1 + (size_t)(koff + k0) * H1 + htile * 32 + m;
            #pragma unroll
            for (int e = 0; e < 8; ++e)
                af[e] = (_Float16)wb[(size_t)e * H1];     // coalesced per e
            const half8 bf = *(const half8*)&xlds[xrow0 + m][k0];
            acc = __builtin_amdgcn_mfma_f32_32x32x16_f16(af, bf, acc, 0, 0, 0);
        }
        _Float16* drow = dstbase + (size_t)m * PAD;       // D col -> LDS row
        #pragma unroll
        for (int q = 0; q < 4; ++q) {                     // packed b64 stores
            half4 hv;
            #pragma unroll
            for (int jj = 0; jj < 4; ++jj) {
                const int r  = q * 4 + jj;                // hl=(r&3)+8(r>>2)+4hi
                const int hg = htile * 32 + 8 * q + 4 * hi + jj;
                float v = acc[r];
                if (bias) v += bias[hg];
                hv[jj] = (_Float16)v;
            }
            *(half4*)(drow + htile * 32 + 8 * q + 4 * hi) = hv;
        }
    }

    // ============ per-wave edge init (weights straight from global) =======
    half8 wa[4];
    #pragma unroll
    for (int c4 = 0; c4 < 4; ++c4)
        #pragma unroll
        for (int e = 0; e < 8; ++e)
            wa[c4][e] = (_Float16)W2[(16 * c4 + hi * 8 + e) * H2 + jn];

    f32x16 ci;
    #pragma unroll
    for (int r = 0; r < 16; ++r) {           // D row mapping [m74/m101]
        const int row = (r & 3) + 8 * (r >> 2) + 4 * hi;
        ci[r] = b2[row];
    }
    // W3 paired for the packed epilogue (R10 layout, verified)
    f32x2 w32[8];
    #pragma unroll
    for (int q = 0; q < 8; ++q) {
        const int row = ((2 * q) & 3) + 8 * (q >> 1) + 4 * hi;
        w32[q] = (f32x2){W3[row], W3[row + 1]};
    }
    const float b3v = b3[0];

    __syncthreads();   // phase A LDS writes visible to all waves

    // wave's phase-B assignment: row-group (wv>>1)*16, j-half (wv&1)*32
    const int rowgrp = wv >> 1;
    const int jhalf  = wv & 1;

    // B-frags (pj side) from LDS: row jhalf*32+jn, k-slices 16c + hi*8
    const _Float16* pr = &pjlds[jhalf * 32 + jn][hi * 8];
    const half8 qj0 = *(const half8*)(pr);
    const half8 qj1 = *(const half8*)(pr + 16);
    const half8 qj2 = *(const half8*)(pr + 32);
    const half8 qj3 = *(const half8*)(pr + 48);

    // R10 packed epilogue (incl. cross-half shfl)
    auto epi = [&](const f32x16& dd) -> float {
        const f32x2 z2 = {0.f, 0.f};
        f32x2 s[4] = {z2, z2, z2, z2};
        #pragma unroll
        for (int q = 0; q < 8; ++q) {
            f32x2 dp = {dd[2 * q], dd[2 * q + 1]};
            dp = __builtin_elementwise_max(dp, z2);
            s[q & 3] = __builtin_elementwise_fma(dp, w32[q], s[q & 3]);
        }
        const f32x2 t01 = s[0] + s[1];
        const f32x2 t23 = s[2] + s[3];
        const f32x2 tt  = t01 + t23;
        float p = tt[0] + tt[1];
        p += __shfl_xor(p, 32);   // lane-halves hold complementary rows
        return p;
    };

    // ============ phase B: software-pipelined 16 row-steps ================
    const _Float16* irbase = &plds[rowgrp * 16][hi * 8];
    float* obase = out + (size_t)(b * NN + i0 + rowgrp * 16) * NN
                       + j0 + jhalf * 32 + jn;

    // ---- prologue: e(0), dP = mfma(step 0), e(1) ----
    half8 e0 = addrelu8(qj0, *(const half8*)(irbase));
    half8 e1 = addrelu8(qj1, *(const half8*)(irbase + 16));
    half8 e2 = addrelu8(qj2, *(const half8*)(irbase + 32));
    half8 e3 = addrelu8(qj3, *(const half8*)(irbase + 48));
    f32x16 dP;
    dP = __builtin_amdgcn_mfma_f32_32x32x16_f16(wa[0], e0, ci, 0, 0, 0);
    dP = __builtin_amdgcn_mfma_f32_32x32x16_f16(wa[1], e1, dP, 0, 0, 0);
    dP = __builtin_amdgcn_mfma_f32_32x32x16_f16(wa[2], e2, dP, 0, 0, 0);
    dP = __builtin_amdgcn_mfma_f32_32x32x16_f16(wa[3], e3, dP, 0, 0, 0);
    {
        const _Float16* ir = irbase + PAD;
        e0 = addrelu8(qj0, *(const half8*)(ir));
        e1 = addrelu8(qj1, *(const half8*)(ir + 16));
        e2 = addrelu8(qj2, *(const half8*)(ir + 32));
        e3 = addrelu8(qj3, *(const half8*)(ir + 48));
    }
    float pe = 0.f;

    #pragma unroll 2
    for (int t = 1; t < 16; ++t) {
        // 1. prefetch LDS row for step t+1
        const int tn = (t < 15) ? t + 1 : 15;
        const _Float16* ir = irbase + tn * PAD;
        const half8 m0 = *(const half8*)(ir);
        const half8 m1 = *(const half8*)(ir + 16);
        const half8 m2 = *(const half8*)(ir + 32);
        const half8 m3 = *(const half8*)(ir + 48);
        // 2. MFMA chain of step t on e (built last iteration)
        f32x16 d;
        d = __builtin_amdgcn_mfma_f32_32x32x16_f16(wa[0], e0, ci, 0, 0, 0);
        d = __builtin_amdgcn_mfma_f32_32x32x16_f16(wa[1], e1, d,  0, 0, 0);
        d = __builtin_amdgcn_mfma_f32_32x32x16_f16(wa[2], e2, d,  0, 0, 0);
        d = __builtin_amdgcn_mfma_f32_32x32x16_f16(wa[3], e3, d,  0, 0, 0);
        // 3. epilogue of step t-1 (independent of the chain above)
        const float p = epi(dP);
        if ((t - 1) & 1) {                   // t even: store pair (t-2, t-1)
            const float v = hi ? p : pe;     // hi half stores the odd row
            obase[(size_t)(t - 2 + hi) * NN] = v + b3v;
        } else {
            pe = p;
        }
        // 4. build E for step t+1 (independent of the chain above)
        e0 = addrelu8(qj0, m0);
        e1 = addrelu8(qj1, m1);
        e2 = addrelu8(qj2, m2);
        e3 = addrelu8(qj3, m3);
        dP = d;
    }
    // ---- tail: epilogue of step 15, store pair (14,15) ----
    {
        const float p = epi(dP);
        const float v = hi ? p : pe;
        obase[(size_t)(14 + hi) * NN] = v + b3v;
    }
}

extern "C" void kernel_launch(void* const* d_in, const int* in_sizes, int n_in,
                              void* d_out, int out_size, void* d_ws, size_t ws_size,
                              hipStream_t stream) {
    const float* x  = (const float*)d_in[0];
    // d_in[1] = adj (UNUSED by reference), d_in[2] = mask (UNUSED)
    const float* W1 = (const float*)d_in[3];
    const float* b1 = (const float*)d_in[4];
    const float* W2 = (const float*)d_in[5];
    const float* b2 = (const float*)d_in[6];
    const float* W3 = (const float*)d_in[7];
    const float* b3 = (const float*)d_in[8];
    float* out = (float*)d_out;

    // single self-sufficient launch; 512 blocks x 512 threads
    fused_kernel<<<BB * NN * NN / (64 * 64), 512, 0, stream>>>(
        x, W1, b1, W2, b2, W3, b3, out);
}

// Round 13
// 22.825 us; speedup vs baseline: 9.4568x; 1.0075x over previous
//
#include <hip/hip_runtime.h>

#define BB 2
#define NN 1024
#define FF 128
#define H1 64
#define H2 32
#define XPAD 136  // x-row stride in f16 (128+8)
#define PAD 72    // p-row stride in f16 (64+8)

typedef __attribute__((ext_vector_type(4))) _Float16 half4;   // 4 f16 (8B)
typedef __attribute__((ext_vector_type(8))) _Float16 half8;   // 8 f16 (4 VGPR)
typedef __attribute__((ext_vector_type(16))) float f32x16;    // 32x32 MFMA acc
typedef __attribute__((ext_vector_type(2))) float f32x2;      // v_pk_*_f32

// e = relu(a + b) in packed f16: 4x v_pk_add_f16 + 4x v_pk_max_f16
__device__ inline half8 addrelu8(half8 a, half8 b) {
    half8 s = a + b;
    const half8 z = {};
    return __builtin_elementwise_max(s, z);
}

// ---------------------------------------------------------------------------
// ZERO-SYNC full fusion, v6 = v5 with ONE knob: __launch_bounds__(512,2).
// R12 counter algebra exposed ~212 VALU inst/step vs ~55 in source; R9's
// VGPR_Count=64 with ~140 live values under the (.,4) 128-reg cap means the
// allocator pushed accumulators (ci/d/dP/w32) into AGPRs -> v_accvgpr_read/
// write traffic on every epilogue access and pipeline rotate, in BOTH
// phases. (Also explains R10/R11 nulls: the dominant insts weren't the
// edited ones.) (512,2) doubles the budget to 256 unified regs -> all-VGPR
// allocation, zero accvgpr shuffling. Occupancy 4->2 waves/SIMD; acceptable
// because issue-bound, and the R11 pipeline covers MFMA latency intra-wave.
// Everything else byte-identical to R12 (v5).
// ---------------------------------------------------------------------------
__global__ __launch_bounds__(512, 2) void fused_kernel(
    const float* __restrict__ x, const float* __restrict__ W1,
    const float* __restrict__ b1, const float* __restrict__ W2,
    const float* __restrict__ b2, const float* __restrict__ W3,
    const float* __restrict__ b3, float* __restrict__ out)
{
    __shared__ __align__(16) _Float16 xlds[128][XPAD];  // 34.8 KB staged x
    __shared__ __align__(16) _Float16 plds[64][PAD];    // 9.2 KB pib rows
    __shared__ __align__(16) _Float16 pjlds[64][PAD];   // 9.2 KB pj rows

    const int tid  = threadIdx.x;
    const int lane = tid & 63;
    const int wv   = tid >> 6;                // 0..7
    const int bid  = blockIdx.x;

    const int b   = bid >> 8;                 // 256 blocks per batch
    const int rem = bid & 255;
    const int i0  = (rem >> 4) * 64;          // 16 i-tiles (64 rows each)
    const int j0  = (rem & 15) * 64;          // 16 j-tiles (64 cols each)
    const int jn  = lane & 31;                // m/n lane index
    const int hi  = lane >> 5;                // k-group half
    const int m   = jn;

    // ============ stage: 128 x-rows -> xlds (coalesced, f16) ==============
    // rows 0..63 = i-rows i0..i0+63; rows 64..127 = j-rows j0..j0+63.
    {
        const int xb_i = b * NN + i0, xb_j = b * NN + j0 - 64;
        #pragma unroll
        for (int it = 0; it < 8; ++it) {
            const int idx = tid + it * 512;
            const int row = idx >> 5, c4 = (idx & 31) * 4;
            const int gr  = (row < 64 ? xb_i : xb_j) + row;
            const float4 v = *(const float4*)(x + (size_t)gr * FF + c4);
            half4 hv = {(_Float16)v.x, (_Float16)v.y,
                        (_Float16)v.z, (_Float16)v.w};
            *(half4*)&xlds[row][c4] = hv;
        }
    }
    __syncthreads();

    // ============ phase A: 8 gemm units, ONE per wave (balanced) ==========
    //   wv0/1: pib rows  0-31 (htile 0/1)   wv2/3: pib rows 32-63
    //   wv4/5: pj  rows  0-31               wv6/7: pj  rows 32-63
    {
        const int xrow0 = ((wv & 2) ? 32 : 0) + ((wv & 4) ? 64 : 0);
        const int htile = wv & 1;
        const int koff  = (wv & 4) ? 0 : FF;
        _Float16* dstbase = (wv & 4) ? &pjlds[xrow0 - 64][0] : &plds[xrow0][0];
        const float* bias = (wv & 4) ? nullptr : b1;

        f32x16 acc = {};
        #pragma unroll
        for (int ks = 0; ks < 8; ++ks) {
            const int k0 = ks * 16 + hi * 8;
            half8 af;
            const float* wb = W1 + (size_t)(koff + k0) * H1 + htile * 32 + m;
            #pragma unroll
            for (int e = 0; e < 8; ++e)
                af[e] = (_Float16)wb[(size_t)e * H1];     // coalesced per e
            const half8 bf = *(const half8*)&xlds[xrow0 + m][k0];
            acc = __builtin_amdgcn_mfma_f32_32x32x16_f16(af, bf, acc, 0, 0, 0);
        }
        _Float16* drow = dstbase + (size_t)m * PAD;       // D col -> LDS row
        #pragma unroll
        for (int q = 0; q < 4; ++q) {                     // packed b64 stores
            half4 hv;
            #pragma unroll
            for (int jj = 0; jj < 4; ++jj) {
                const int r  = q * 4 + jj;                // hl=(r&3)+8(r>>2)+4hi
                const int hg = htile * 32 + 8 * q + 4 * hi + jj;
                float v = acc[r];
                if (bias) v += bias[hg];
                hv[jj] = (_Float16)v;
            }
            *(half4*)(drow + htile * 32 + 8 * q + 4 * hi) = hv;
        }
    }

    // ============ per-wave edge init (weights straight from global) =======
    half8 wa[4];
    #pragma unroll
    for (int c4 = 0; c4 < 4; ++c4)
        #pragma unroll
        for (int e = 0; e < 8; ++e)
            wa[c4][e] = (_Float16)W2[(16 * c4 + hi * 8 + e) * H2 + jn];

    f32x16 ci;
    #pragma unroll
    for (int r = 0; r < 16; ++r) {           // D row mapping [m74/m101]
        const int row = (r & 3) + 8 * (r >> 2) + 4 * hi;
        ci[r] = b2[row];
    }
    // W3 paired for the packed epilogue (R10 layout, verified)
    f32x2 w32[8];
    #pragma unroll
    for (int q = 0; q < 8; ++q) {
        const int row = ((2 * q) & 3) + 8 * (q >> 1) + 4 * hi;
        w32[q] = (f32x2){W3[row], W3[row + 1]};
    }
    const float b3v = b3[0];

    __syncthreads();   // phase A LDS writes visible to all waves

    // wave's phase-B assignment: row-group (wv>>1)*16, j-half (wv&1)*32
    const int rowgrp = wv >> 1;
    const int jhalf  = wv & 1;

    // B-frags (pj side) from LDS: row jhalf*32+jn, k-slices 16c + hi*8
    const _Float16* pr = &pjlds[jhalf * 32 + jn][hi * 8];
    const half8 qj0 = *(const half8*)(pr);
    const half8 qj1 = *(const half8*)(pr + 16);
    const half8 qj2 = *(const half8*)(pr + 32);
    const half8 qj3 = *(const half8*)(pr + 48);

    // R10 packed epilogue (incl. cross-half shfl)
    auto epi = [&](const f32x16& dd) -> float {
        const f32x2 z2 = {0.f, 0.f};
        f32x2 s[4] = {z2, z2, z2, z2};
        #pragma unroll
        for (int q = 0; q < 8; ++q) {
            f32x2 dp = {dd[2 * q], dd[2 * q + 1]};
            dp = __builtin_elementwise_max(dp, z2);
            s[q & 3] = __builtin_elementwise_fma(dp, w32[q], s[q & 3]);
        }
        const f32x2 t01 = s[0] + s[1];
        const f32x2 t23 = s[2] + s[3];
        const f32x2 tt  = t01 + t23;
        float p = tt[0] + tt[1];
        p += __shfl_xor(p, 32);   // lane-halves hold complementary rows
        return p;
    };

    // ============ phase B: software-pipelined 16 row-steps ================
    const _Float16* irbase = &plds[rowgrp * 16][hi * 8];
    float* obase = out + (size_t)(b * NN + i0 + rowgrp * 16) * NN
                       + j0 + jhalf * 32 + jn;

    // ---- prologue: e(0), dP = mfma(step 0), e(1) ----
    half8 e0 = addrelu8(qj0, *(const half8*)(irbase));
    half8 e1 = addrelu8(qj1, *(const half8*)(irbase + 16));
    half8 e2 = addrelu8(qj2, *(const half8*)(irbase + 32));
    half8 e3 = addrelu8(qj3, *(const half8*)(irbase + 48));
    f32x16 dP;
    dP = __builtin_amdgcn_mfma_f32_32x32x16_f16(wa[0], e0, ci, 0, 0, 0);
    dP = __builtin_amdgcn_mfma_f32_32x32x16_f16(wa[1], e1, dP, 0, 0, 0);
    dP = __builtin_amdgcn_mfma_f32_32x32x16_f16(wa[2], e2, dP, 0, 0, 0);
    dP = __builtin_amdgcn_mfma_f32_32x32x16_f16(wa[3], e3, dP, 0, 0, 0);
    {
        const _Float16* ir = irbase + PAD;
        e0 = addrelu8(qj0, *(const half8*)(ir));
        e1 = addrelu8(qj1, *(const half8*)(ir + 16));
        e2 = addrelu8(qj2, *(const half8*)(ir + 32));
        e3 = addrelu8(qj3, *(const half8*)(ir + 48));
    }
    float pe = 0.f;

    #pragma unroll 2
    for (int t = 1; t < 16; ++t) {
        // 1. prefetch LDS row for step t+1
        const int tn = (t < 15) ? t + 1 : 15;
        const _Float16* ir = irbase + tn * PAD;
        const half8 m0 = *(const half8*)(ir);
        const half8 m1 = *(const half8*)(ir + 16);
        const half8 m2 = *(const half8*)(ir + 32);
        const half8 m3 = *(const half8*)(ir + 48);
        // 2. MFMA chain of step t on e (built last iteration)
        f32x16 d;
        d = __builtin_amdgcn_mfma_f32_32x32x16_f16(wa[0], e0, ci, 0, 0, 0);
        d = __builtin_amdgcn_mfma_f32_32x32x16_f16(wa[1], e1, d,  0, 0, 0);
        d = __builtin_amdgcn_mfma_f32_32x32x16_f16(wa[2], e2, d,  0, 0, 0);
        d = __builtin_amdgcn_mfma_f32_32x32x16_f16(wa[3], e3, d,  0, 0, 0);
        // 3. epilogue of step t-1 (independent of the chain above)
        const float p = epi(dP);
        if ((t - 1) & 1) {                   // t even: store pair (t-2, t-1)
            const float v = hi ? p : pe;     // hi half stores the odd row
            obase[(size_t)(t - 2 + hi) * NN] = v + b3v;
        } else {
            pe = p;
        }
        // 4. build E for step t+1 (independent of the chain above)
        e0 = addrelu8(qj0, m0);
        e1 = addrelu8(qj1, m1);
        e2 = addrelu8(qj2, m2);
        e3 = addrelu8(qj3, m3);
        dP = d;
    }
    // ---- tail: epilogue of step 15, store pair (14,15) ----
    {
        const float p = epi(dP);
        const float v = hi ? p : pe;
        obase[(size_t)(14 + hi) * NN] = v + b3v;
    }
}

extern "C" void kernel_launch(void* const* d_in, const int* in_sizes, int n_in,
                              void* d_out, int out_size, void* d_ws, size_t ws_size,
                              hipStream_t stream) {
    const float* x  = (const float*)d_in[0];
    // d_in[1] = adj (UNUSED by reference), d_in[2] = mask (UNUSED)
    const float* W1 = (const float*)d_in[3];
    const float* b1 = (const float*)d_in[4];
    const float* W2 = (const float*)d_in[5];
    const float* b2 = (const float*)d_in[6];
    const float* W3 = (const float*)d_in[7];
    const float* b3 = (const float*)d_in[8];
    float* out = (float*)d_out;

    // single self-sufficient launch; 512 blocks x 512 threads
    fused_kernel<<<BB * NN * NN / (64 * 64), 512, 0, stream>>>(
        x, W1, b1, W2, b2, W3, b3, out);
}